// Round 19
// baseline (42.370 us; speedup 1.0000x reference)
//
#include <hip/hip_runtime.h>

#define KS    7
#define RAD   3
#define TS    8             // 8x8 tile per WAVE (64-thread block = 1 wave)
#define HC    14            // halo cols
#define HR    14            // halo rows
#define PAIRS 8             // col-pairs per parity row (7 used + 1 pad)
#define ROWST (2*PAIRS)     // 16 sites per halo row
#define NSITE (HR*ROWST)    // 224 sites
#define H     256
#define W     256
#define HWp   (H*W)
#define NTASK (HR*4*4)      // 224 input tasks/group: 14 rows x 4 quads x 4 cpairs

typedef __fp16    h2raw __attribute__((ext_vector_type(2)));
typedef _Float16  f16x2 __attribute__((ext_vector_type(2)));

__device__ __forceinline__ unsigned pk(float a, float b) {
    h2raw h = __builtin_amdgcn_cvt_pkrtz(a, b);
    return __builtin_bit_cast(unsigned, h);
}
__device__ __forceinline__ f16x2 bch(unsigned u) {
    return __builtin_bit_cast(f16x2, u);
}

#if __has_builtin(__builtin_amdgcn_fdot2)
__device__ __forceinline__ float fdot2(f16x2 a, f16x2 b, float c) {
    return __builtin_amdgcn_fdot2(a, b, c, false);
}
#else
__device__ __forceinline__ float fdot2(f16x2 a, f16x2 b, float c) {
    return c + (float)a.x * (float)b.x + (float)a.y * (float)b.y;
}
#endif

// compiler-only reorder fence: zero instructions; HW LDS is in-order per wave
#define FENCE() asm volatile("" ::: "memory")

// ---- issue group g's global loads into registers (no LDS touch) ----
#define ISSUE_IN(g) do {                                                    \
    _Pragma("unroll")                                                       \
    for (int j = 0; j < 4; ++j) {                                           \
        int t = tid + j * 64;                                               \
        iA[j] = make_float4(0.f, 0.f, 0.f, 0.f); iB[j] = iA[j];             \
        if (t < NTASK) {                                                    \
            int row = t >> 4;                                               \
            int rem = t & 15;                                               \
            int q   = rem >> 2;                                             \
            int cp  = rem & 3;                                              \
            int gy  = y0 - RAD + row;                                       \
            int gxb = x0 - 4 + 4 * q;                                       \
            if (gy >= 0 && gy < H && gxb >= 0 && gxb < W) {                 \
                const float* p = inb + (size_t)((g) * 8 + 2 * cp) * HWp     \
                                 + gy * W + gxb;                            \
                iA[j] = *(const float4*)p;                                  \
                iB[j] = *(const float4*)(p + HWp);                          \
            }                                                               \
        }                                                                   \
    }                                                                       \
} while (0)

// ---- pack staged registers and write them into dtu[buf] ----
#define WRITE_IN(buf) do {                                                  \
    _Pragma("unroll")                                                       \
    for (int j = 0; j < 4; ++j) {                                           \
        int t = tid + j * 64;                                               \
        if (t < NTASK) {                                                    \
            int row = t >> 4;                                               \
            int rem = t & 15;                                               \
            int q   = rem >> 2;                                             \
            int cp  = rem & 3;                                              \
            int base = row * ROWST;                                         \
            unsigned* dst = &dtu[(buf)][cp];                                \
            if (q != 0) dst[(base + PAIRS + 2 * q - 1) * 4] = pk(iA[j].x, iB[j].x); \
            dst[(base + 2 * q) * 4]         = pk(iA[j].y, iB[j].y);         \
            dst[(base + PAIRS + 2 * q) * 4] = pk(iA[j].z, iB[j].z);         \
            if (q != 3) dst[(base + 2 * q + 1) * 4] = pk(iA[j].w, iB[j].w); \
        }                                                                   \
    }                                                                       \
} while (0)

// ---- apply group g from dtu[buf] with register-resident packed weights ----
#define APPLY(buf, g) do {                                                  \
    const uint4* dg = (const uint4*)&dtu[(buf)][0];                         \
    float acc[8];                                                           \
    _Pragma("unroll") for (int c = 0; c < 8; ++c) acc[c] = 0.f;             \
    _Pragma("unroll")                                                       \
    for (int i = 0; i < KS; ++i) {                                          \
        const int rb = (ty + i) * ROWST;                                    \
        uint4 rq[KS];                                                       \
        _Pragma("unroll")                                                   \
        for (int k = 0; k < KS; ++k) rq[k] = dg[rb + colAdd[k]];            \
        f16x2 A0 = (f16x2)0, A1 = (f16x2)0, A2 = (f16x2)0, A3 = (f16x2)0;   \
        _Pragma("unroll")                                                   \
        for (int k = 0; k < KS; ++k) {                                      \
            f16x2 wh = bch(wkp[i * KS + k]);                                \
            A0 = wh * bch(rq[k].x) + A0;                                    \
            A1 = wh * bch(rq[k].y) + A1;                                    \
            A2 = wh * bch(rq[k].z) + A2;                                    \
            A3 = wh * bch(rq[k].w) + A3;                                    \
        }                                                                   \
        acc[0] += (float)A0.x; acc[1] += (float)A0.y;                       \
        acc[2] += (float)A1.x; acc[3] += (float)A1.y;                       \
        acc[4] += (float)A2.x; acc[5] += (float)A2.y;                       \
        acc[6] += (float)A3.x; acc[7] += (float)A3.y;                       \
    }                                                                       \
    float* ob = out + ((size_t)b * 32 + (g) * 8) * HWp                      \
                + (size_t)Yo * W + Xo;                                      \
    _Pragma("unroll")                                                       \
    for (int c = 0; c < 8; ++c) ob[(size_t)c * HWp] = acc[c] * inv;         \
} while (0)

__global__ __launch_bounds__(64, 3)
void bilateral_kernel(const float* __restrict__ in,      // [B][32][H][W]
                      const float* __restrict__ guide,   // [B][3][H][W]
                      const float* __restrict__ sigma_p, // [1]
                      float* __restrict__ out)           // [B][32][H][W]
{
    // wave-private LDS; parity-split site: (row,col) -> row*16 + (col&1)*8 + (col>>1)
    __shared__ uint2 gt2[NSITE];                          // {pk(x~,y~), pk(z~,q~)}
    __shared__ __align__(16) unsigned dtu[2][NSITE * 4];  // double-buffered 8ch fp16

    const int tid = threadIdx.x;
    const int tx  = tid & 7;             // output col 0..7
    const int ty  = tid >> 3;            // output row 0..7
    const int x0  = blockIdx.x * TS;
    const int y0  = blockIdx.y * TS;
    const int b   = blockIdx.z;

    const float* gb  = guide + (size_t)b * 3  * HWp;
    const float* inb = in    + (size_t)b * 32 * HWp;

    const float sigma = sigma_p[0];
    const float isig2 = 1.0f / (sigma * sigma);
    const float L2E   = 1.442695041f;          // log2(e)
    const float SQL   = 1.201122409f;          // sqrt(log2(e))
    float lnT2[KS];
#pragma unroll
    for (int i = 0; i < KS; ++i) {
        float r = (float)(i - RAD);
        lnT2[i] = -0.5f * r * r * isig2 * L2E;
    }

    // ---- issue guide loads (56 quad-tasks), then group-0 input loads ----
    float4 gX = make_float4(0.f, 0.f, 0.f, 0.f), gY = gX, gZ = gX;
    int grow = 0, gq = 0;
    if (tid < HR * 4) {
        grow = tid >> 2; gq = tid & 3;
        int gy  = y0 - RAD + grow;
        int gxb = x0 - 4 + 4 * gq;                // 4-aligned quad
        if (gy >= 0 && gy < H && gxb >= 0 && gxb < W) {
            const float* p = gb + gy * W + gxb;
            gX = *(const float4*)p;
            gY = *(const float4*)(p + HWp);
            gZ = *(const float4*)(p + 2 * HWp);
        }
    }
    float4 iA[4], iB[4];
    ISSUE_IN(0);                                  // g0 loads fly under guide+weights

    // ---- guide pack + LDS write (cols 4q-1 .. 4q+2) ----
    if (tid < HR * 4) {
        int base = grow * ROWST;
        const float xs[4] = {gX.x, gX.y, gX.z, gX.w};
        const float ys[4] = {gY.x, gY.y, gY.z, gY.w};
        const float zs[4] = {gZ.x, gZ.y, gZ.z, gZ.w};
        const int   st[4] = {base + PAIRS + 2 * gq - 1, base + 2 * gq,
                             base + PAIRS + 2 * gq,     base + 2 * gq + 1};
#pragma unroll
        for (int j = 0; j < 4; ++j) {
            if ((gq == 0 && j == 0) || (gq == 3 && j == 3)) continue;  // col -1/14
            float ax = xs[j] * SQL, ay = ys[j] * SQL, az = zs[j] * SQL;
            float qv = -0.5f * (ax * ax + ay * ay + az * az);
            gt2[st[j]] = make_uint2(pk(ax, ay), pk(az, qv));
        }
    }
    FENCE();                                      // gt2 writes before reads

    // ---- per-column site offsets (hoisted) ----
    int colAdd[KS];
#pragma unroll
    for (int k = 0; k < KS; ++k) {
        int col = tx + k;
        colAdd[k] = (col & 1) * PAIRS + (col >> 1);
    }

    // ---- weights (g0 loads in flight underneath) ----
    const int ccol = tx + RAD;
    uint2 cr = gt2[(ty + RAD) * ROWST + (ccol & 1) * PAIRS + (ccol >> 1)];
    const f16x2 cxy = bch(cr.x);
    f16x2 czq = bch(cr.y);
    const float qc = (float)czq.y;
    f16x2 cz1;
    cz1.x = czq.x; cz1.y = (_Float16)1.0f;

    unsigned wkp[KS * KS];
    float nsum = 0.f;
#pragma unroll
    for (int i = 0; i < KS; ++i) {
        const int rb = (ty + i) * ROWST;
        const float Qi = lnT2[i] + qc;
#pragma unroll
        for (int k = 0; k < KS; ++k) {
            uint2 g = gt2[rb + colAdd[k]];
            float e = fdot2(bch(g.x), cxy, fdot2(bch(g.y), cz1, Qi + lnT2[k]));
            float w = exp2f(e);
            nsum += w;
            wkp[i * KS + k] = pk(w, w);
        }
    }
    const float inv = 1.f / nsum;   // >= center weight ~= 1, never 0
    const int Xo = x0 + tx, Yo = y0 + ty;

    // ---- barrier-free wave-serial pipeline, double-buffered LDS ----
    WRITE_IN(0);                  // buf0 <- g0 (vmcnt hidden under guide+weights)
    FENCE();
    ISSUE_IN(1);                  // g1 loads fly under apply(g0)
    APPLY(0, 0);
    WRITE_IN(1);                  // buf1 <- g1
    FENCE();
    ISSUE_IN(2);
    APPLY(1, 1);
    WRITE_IN(0);                  // buf0 <- g2 (apply g0 done: wave-serial)
    FENCE();
    ISSUE_IN(3);
    APPLY(0, 2);
    WRITE_IN(1);                  // buf1 <- g3
    FENCE();
    APPLY(1, 3);
}

extern "C" void kernel_launch(void* const* d_in, const int* in_sizes, int n_in,
                              void* d_out, int out_size, void* d_ws, size_t ws_size,
                              hipStream_t stream) {
    const float* in    = (const float*)d_in[0];
    const float* guide = (const float*)d_in[1];
    const float* sigma = (const float*)d_in[2];
    float* out = (float*)d_out;
    dim3 grid(W / TS, H / TS, 2);   // 32 x 32 x 2 = 2048 one-wave blocks
    bilateral_kernel<<<grid, dim3(64), 0, stream>>>(in, guide, sigma, out);
}

// Round 20
// 24.944 us; speedup vs baseline: 1.6986x; 1.6986x over previous
//
#include <hip/hip_runtime.h>

#define KS    7
#define RAD   3
#define TW    16            // tile width (output px)
#define TH    8             // tile height
#define HR    14            // halo rows = TH + 2*RAD
#define NQ    6             // staging quads per row (cols x0-4 .. x0+19)
#define PAIRS 12            // col-pairs per parity row (11 used + 1 pad)
#define ROWST (2*PAIRS)     // 24 sites per halo row
#define NSITE (HR*ROWST)    // 336 sites
#define H     256
#define W     256
#define HWp   (H*W)
#define NTASK (HR*NQ*4)     // 336 input tasks/group
#define NTHR  128

typedef __fp16    h2raw __attribute__((ext_vector_type(2)));
typedef _Float16  f16x2 __attribute__((ext_vector_type(2)));

__device__ __forceinline__ unsigned pk(float a, float b) {
    h2raw h = __builtin_amdgcn_cvt_pkrtz(a, b);
    return __builtin_bit_cast(unsigned, h);
}
__device__ __forceinline__ f16x2 bch(unsigned u) {
    return __builtin_bit_cast(f16x2, u);
}

#if __has_builtin(__builtin_amdgcn_fdot2)
__device__ __forceinline__ float fdot2(f16x2 a, f16x2 b, float c) {
    return __builtin_amdgcn_fdot2(a, b, c, false);
}
#else
__device__ __forceinline__ float fdot2(f16x2 a, f16x2 b, float c) {
    return c + (float)a.x * (float)b.x + (float)a.y * (float)b.y;
}
#endif

// ---- issue group g's global loads into registers (no LDS touch) ----
#define ISSUE_IN(g) do {                                                    \
    _Pragma("unroll")                                                       \
    for (int j = 0; j < 3; ++j) {                                           \
        int t = tid + j * NTHR;                                             \
        iA[j] = make_float4(0.f, 0.f, 0.f, 0.f); iB[j] = iA[j];             \
        if (t < NTASK) {                                                    \
            int row = t / (NQ * 4);                                         \
            int rem = t - row * (NQ * 4);                                   \
            int q   = rem >> 2;                                             \
            int cp  = rem & 3;                                              \
            int gy  = y0 - RAD + row;                                       \
            int gxb = x0 - 4 + 4 * q;                                       \
            if (gy >= 0 && gy < H && gxb >= 0 && gxb < W) {                 \
                const float* p = inb + (size_t)((g) * 8 + 2 * cp) * HWp     \
                                 + gy * W + gxb;                            \
                iA[j] = *(const float4*)p;                                  \
                iB[j] = *(const float4*)(p + HWp);                          \
            }                                                               \
        }                                                                   \
    }                                                                       \
} while (0)

// ---- pack staged registers and write them to dtu[g] ----
// quad q covers cols 4q-1 .. 4q+2 (skip col -1 at q=0, col 22 at q=NQ-1)
#define WRITE_IN(g) do {                                                    \
    _Pragma("unroll")                                                       \
    for (int j = 0; j < 3; ++j) {                                           \
        int t = tid + j * NTHR;                                             \
        if (t < NTASK) {                                                    \
            int row = t / (NQ * 4);                                         \
            int rem = t - row * (NQ * 4);                                   \
            int q   = rem >> 2;                                             \
            int cp  = rem & 3;                                              \
            int base = row * ROWST;                                         \
            unsigned* dst = &dtu[(g)][cp];                                  \
            if (q != 0) dst[(base + PAIRS + 2 * q - 1) * 4] = pk(iA[j].x, iB[j].x); \
            dst[(base + 2 * q) * 4]         = pk(iA[j].y, iB[j].y);         \
            dst[(base + PAIRS + 2 * q) * 4] = pk(iA[j].z, iB[j].z);         \
            if (q != NQ - 1) dst[(base + 2 * q + 1) * 4] = pk(iA[j].w, iB[j].w); \
        }                                                                   \
    }                                                                       \
} while (0)

// ---- apply group g with the register-resident packed weights ----
#define APPLY(g) do {                                                       \
    const uint4* dg = (const uint4*)&dtu[(g)][0];                           \
    float acc[8];                                                           \
    _Pragma("unroll") for (int c = 0; c < 8; ++c) acc[c] = 0.f;             \
    _Pragma("unroll")                                                       \
    for (int i = 0; i < KS; ++i) {                                          \
        const int rb = (ty + i) * ROWST;                                    \
        uint4 rq[KS];                                                       \
        _Pragma("unroll")                                                   \
        for (int k = 0; k < KS; ++k) rq[k] = dg[rb + colAdd[k]];            \
        f16x2 A0 = (f16x2)0, A1 = (f16x2)0, A2 = (f16x2)0, A3 = (f16x2)0;   \
        _Pragma("unroll")                                                   \
        for (int k = 0; k < KS; ++k) {                                      \
            f16x2 wh = bch(wkp[i * KS + k]);                                \
            A0 = wh * bch(rq[k].x) + A0;                                    \
            A1 = wh * bch(rq[k].y) + A1;                                    \
            A2 = wh * bch(rq[k].z) + A2;                                    \
            A3 = wh * bch(rq[k].w) + A3;                                    \
        }                                                                   \
        acc[0] += (float)A0.x; acc[1] += (float)A0.y;                       \
        acc[2] += (float)A1.x; acc[3] += (float)A1.y;                       \
        acc[4] += (float)A2.x; acc[5] += (float)A2.y;                       \
        acc[6] += (float)A3.x; acc[7] += (float)A3.y;                       \
    }                                                                       \
    float* ob = out + ((size_t)b * 32 + (g) * 8) * HWp                      \
                + (size_t)Yo * W + Xo;                                      \
    _Pragma("unroll")                                                       \
    for (int c = 0; c < 8; ++c) ob[(size_t)c * HWp] = acc[c] * inv;         \
} while (0)

__global__ __launch_bounds__(NTHR, 2)
void bilateral_kernel(const float* __restrict__ in,      // [B][32][H][W]
                      const float* __restrict__ guide,   // [B][3][H][W]
                      const float* __restrict__ sigma_p, // [1]
                      float* __restrict__ out)           // [B][32][H][W]
{
    // parity-split site: (row,col) -> row*ROWST + (col&1)*PAIRS + (col>>1)
    __shared__ uint2 gt2[NSITE];                          // {pk(x~,y~), pk(z~,q~)}
    __shared__ __align__(16) unsigned dtu[4][NSITE * 4];  // 4 grp x 8ch fp16/site

    const int tid = threadIdx.x;
    const int tx  = tid & 15;            // output col 0..15
    const int ty  = tid >> 4;            // output row 0..7
    const int x0  = blockIdx.x * TW;
    const int y0  = blockIdx.y * TH;
    const int b   = blockIdx.z;

    const float* gb  = guide + (size_t)b * 3  * HWp;
    const float* inb = in    + (size_t)b * 32 * HWp;

    const float sigma = sigma_p[0];
    const float isig2 = 1.0f / (sigma * sigma);
    const float L2E   = 1.442695041f;          // log2(e)
    const float SQL   = 1.201122409f;          // sqrt(log2(e))
    float lnT2[KS];
#pragma unroll
    for (int i = 0; i < KS; ++i) {
        float r = (float)(i - RAD);
        lnT2[i] = -0.5f * r * r * isig2 * L2E;
    }

    // ---- issue guide loads (84 quad-tasks), then group-0 input loads ----
    float4 gX = make_float4(0.f, 0.f, 0.f, 0.f), gY = gX, gZ = gX;
    int grow = 0, gq = 0;
    if (tid < HR * NQ) {
        grow = tid / NQ; gq = tid - grow * NQ;
        int gy  = y0 - RAD + grow;
        int gxb = x0 - 4 + 4 * gq;                // 4-aligned quad
        if (gy >= 0 && gy < H && gxb >= 0 && gxb < W) {
            const float* p = gb + gy * W + gxb;
            gX = *(const float4*)p;
            gY = *(const float4*)(p + HWp);
            gZ = *(const float4*)(p + 2 * HWp);
        }
    }
    float4 iA[3], iB[3];
    ISSUE_IN(0);                                  // g0 loads fly under guide+weights

    // ---- guide pack + LDS write (cols 4q-1 .. 4q+2) ----
    if (tid < HR * NQ) {
        int base = grow * ROWST;
        const float xs[4] = {gX.x, gX.y, gX.z, gX.w};
        const float ys[4] = {gY.x, gY.y, gY.z, gY.w};
        const float zs[4] = {gZ.x, gZ.y, gZ.z, gZ.w};
        const int   st[4] = {base + PAIRS + 2 * gq - 1, base + 2 * gq,
                             base + PAIRS + 2 * gq,     base + 2 * gq + 1};
#pragma unroll
        for (int j = 0; j < 4; ++j) {
            if ((gq == 0 && j == 0) || (gq == NQ - 1 && j == 3)) continue;
            float ax = xs[j] * SQL, ay = ys[j] * SQL, az = zs[j] * SQL;
            float qv = -0.5f * (ax * ax + ay * ay + az * az);
            gt2[st[j]] = make_uint2(pk(ax, ay), pk(az, qv));
        }
    }
    __syncthreads();                              // gt2 ready

    // ---- per-column site offsets (hoisted) ----
    int colAdd[KS];
#pragma unroll
    for (int k = 0; k < KS; ++k) {
        int col = tx + k;
        colAdd[k] = (col & 1) * PAIRS + (col >> 1);
    }

    // ---- weights (g0 loads in flight underneath) ----
    const int ccol = tx + RAD;
    uint2 cr = gt2[(ty + RAD) * ROWST + (ccol & 1) * PAIRS + (ccol >> 1)];
    const f16x2 cxy = bch(cr.x);
    f16x2 czq = bch(cr.y);
    const float qc = (float)czq.y;
    f16x2 cz1;
    cz1.x = czq.x; cz1.y = (_Float16)1.0f;

    unsigned wkp[KS * KS];
    float nsum = 0.f;
#pragma unroll
    for (int i = 0; i < KS; ++i) {
        const int rb = (ty + i) * ROWST;
        const float Qi = lnT2[i] + qc;
#pragma unroll
        for (int k = 0; k < KS; ++k) {
            uint2 g = gt2[rb + colAdd[k]];
            float e = fdot2(bch(g.x), cxy, fdot2(bch(g.y), cz1, Qi + lnT2[k]));
            float w = exp2f(e);
            nsum += w;
            wkp[i * KS + k] = pk(w, w);
        }
    }
    const float inv = 1.f / nsum;   // >= center weight ~= 1, never 0
    const int Xo = x0 + tx, Yo = y0 + ty;

    // ---- pipeline: barrier -> [issue g+1 || apply g -> write g+1] ----
    WRITE_IN(0);
    __syncthreads();              // dtu[0] ready
    ISSUE_IN(1);                  // loads fly under apply(0)
    APPLY(0);
    WRITE_IN(1);
    __syncthreads();              // dtu[1] ready
    ISSUE_IN(2);
    APPLY(1);
    WRITE_IN(2);
    __syncthreads();              // dtu[2] ready
    ISSUE_IN(3);
    APPLY(2);
    WRITE_IN(3);
    __syncthreads();              // dtu[3] ready
    APPLY(3);
}

extern "C" void kernel_launch(void* const* d_in, const int* in_sizes, int n_in,
                              void* d_out, int out_size, void* d_ws, size_t ws_size,
                              hipStream_t stream) {
    const float* in    = (const float*)d_in[0];
    const float* guide = (const float*)d_in[1];
    const float* sigma = (const float*)d_in[2];
    float* out = (float*)d_out;
    dim3 grid(W / TW, H / TH, 2);   // 16 x 32 x 2 = 1024 blocks, 4 per CU
    bilateral_kernel<<<grid, dim3(NTHR), 0, stream>>>(in, guide, sigma, out);
}

// Round 21
// 24.897 us; speedup vs baseline: 1.7018x; 1.0019x over previous
//
#include <hip/hip_runtime.h>

#define KS    7
#define RAD   3
#define TW    16            // tile width (output px)
#define TH    16            // tile height
#define HR    22            // halo rows = TH + 2*RAD
#define NQ    6             // staging quads per row (cols x0-4 .. x0+19)
#define PAIRS 12            // col-pairs per parity row (11 used + 1 pad)
#define ROWST (2*PAIRS)     // 24 sites per halo row
#define NSITE (HR*ROWST)    // 528 sites
#define H     256
#define W     256
#define HWp   (H*W)
#define NTASK (HR*NQ*4)     // 528 input tasks/group
#define NTHR  256

typedef __fp16    h2raw __attribute__((ext_vector_type(2)));
typedef _Float16  f16x2 __attribute__((ext_vector_type(2)));

__device__ __forceinline__ unsigned pk(float a, float b) {
    h2raw h = __builtin_amdgcn_cvt_pkrtz(a, b);
    return __builtin_bit_cast(unsigned, h);
}
__device__ __forceinline__ f16x2 bch(unsigned u) {
    return __builtin_bit_cast(f16x2, u);
}

#if __has_builtin(__builtin_amdgcn_fdot2)
__device__ __forceinline__ float fdot2(f16x2 a, f16x2 b, float c) {
    return __builtin_amdgcn_fdot2(a, b, c, false);
}
#else
__device__ __forceinline__ float fdot2(f16x2 a, f16x2 b, float c) {
    return c + (float)a.x * (float)b.x + (float)a.y * (float)b.y;
}
#endif

// ---- issue group g's global loads into registers (no LDS touch) ----
#define ISSUE_IN(g) do {                                                    \
    _Pragma("unroll")                                                       \
    for (int j = 0; j < 3; ++j) {                                           \
        int t = tid + j * NTHR;                                             \
        iA[j] = make_float4(0.f, 0.f, 0.f, 0.f); iB[j] = iA[j];             \
        if (t < NTASK) {                                                    \
            int row = t / (NQ * 4);                                         \
            int rem = t - row * (NQ * 4);                                   \
            int q   = rem >> 2;                                             \
            int cp  = rem & 3;                                              \
            int gy  = y0 - RAD + row;                                       \
            int gxb = x0 - 4 + 4 * q;                                       \
            if (gy >= 0 && gy < H && gxb >= 0 && gxb < W) {                 \
                const float* p = inb + (size_t)((g) * 8 + 2 * cp) * HWp     \
                                 + gy * W + gxb;                            \
                iA[j] = *(const float4*)p;                                  \
                iB[j] = *(const float4*)(p + HWp);                          \
            }                                                               \
        }                                                                   \
    }                                                                       \
} while (0)

// ---- pack staged registers and write them to dtu[g] ----
// quad q covers halo cols 4q-1 .. 4q+2 (skip col -1 at q=0, col 22 at q=NQ-1)
#define WRITE_IN(g) do {                                                    \
    _Pragma("unroll")                                                       \
    for (int j = 0; j < 3; ++j) {                                           \
        int t = tid + j * NTHR;                                             \
        if (t < NTASK) {                                                    \
            int row = t / (NQ * 4);                                         \
            int rem = t - row * (NQ * 4);                                   \
            int q   = rem >> 2;                                             \
            int cp  = rem & 3;                                              \
            int base = row * ROWST;                                         \
            unsigned* dst = &dtu[(g)][cp];                                  \
            if (q != 0) dst[(base + PAIRS + 2 * q - 1) * 4] = pk(iA[j].x, iB[j].x); \
            dst[(base + 2 * q) * 4]         = pk(iA[j].y, iB[j].y);         \
            dst[(base + PAIRS + 2 * q) * 4] = pk(iA[j].z, iB[j].z);         \
            if (q != NQ - 1) dst[(base + 2 * q + 1) * 4] = pk(iA[j].w, iB[j].w); \
        }                                                                   \
    }                                                                       \
} while (0)

// ---- apply group g with the register-resident packed weights ----
#define APPLY(g) do {                                                       \
    const uint4* dg = (const uint4*)&dtu[(g)][0];                           \
    float acc[8];                                                           \
    _Pragma("unroll") for (int c = 0; c < 8; ++c) acc[c] = 0.f;             \
    _Pragma("unroll")                                                       \
    for (int i = 0; i < KS; ++i) {                                          \
        const int rb = (ty + i) * ROWST;                                    \
        uint4 rq[KS];                                                       \
        _Pragma("unroll")                                                   \
        for (int k = 0; k < KS; ++k) rq[k] = dg[rb + colAdd[k]];            \
        f16x2 A0 = (f16x2)0, A1 = (f16x2)0, A2 = (f16x2)0, A3 = (f16x2)0;   \
        _Pragma("unroll")                                                   \
        for (int k = 0; k < KS; ++k) {                                      \
            f16x2 wh = bch(wkp[i * KS + k]);                                \
            A0 = wh * bch(rq[k].x) + A0;                                    \
            A1 = wh * bch(rq[k].y) + A1;                                    \
            A2 = wh * bch(rq[k].z) + A2;                                    \
            A3 = wh * bch(rq[k].w) + A3;                                    \
        }                                                                   \
        acc[0] += (float)A0.x; acc[1] += (float)A0.y;                       \
        acc[2] += (float)A1.x; acc[3] += (float)A1.y;                       \
        acc[4] += (float)A2.x; acc[5] += (float)A2.y;                       \
        acc[6] += (float)A3.x; acc[7] += (float)A3.y;                       \
    }                                                                       \
    float* ob = out + ((size_t)b * 32 + (g) * 8) * HWp                      \
                + (size_t)Yo * W + Xo;                                      \
    _Pragma("unroll")                                                       \
    for (int c = 0; c < 8; ++c) ob[(size_t)c * HWp] = acc[c] * inv;         \
} while (0)

__global__ __launch_bounds__(NTHR)
void bilateral_kernel(const float* __restrict__ in,      // [B][32][H][W]
                      const float* __restrict__ guide,   // [B][3][H][W]
                      const float* __restrict__ sigma_p, // [1]
                      float* __restrict__ out)           // [B][32][H][W]
{
    // parity-split site: (row,col) -> row*ROWST + (col&1)*PAIRS + (col>>1)
    __shared__ uint2 gt2[NSITE];                          // {pk(x~,y~), pk(z~,q~)}
    __shared__ __align__(16) unsigned dtu[4][NSITE * 4];  // 4 grp x 8ch fp16/site

    const int tid = threadIdx.x;
    const int tx  = tid & 15;            // output col 0..15
    const int ty  = tid >> 4;            // output row 0..15
    const int x0  = blockIdx.x * TW;
    const int y0  = blockIdx.y * TH;
    const int b   = blockIdx.z;

    const float* gb  = guide + (size_t)b * 3  * HWp;
    const float* inb = in    + (size_t)b * 32 * HWp;

    const float sigma = sigma_p[0];
    const float isig2 = 1.0f / (sigma * sigma);
    const float L2E   = 1.442695041f;          // log2(e)
    const float SQL   = 1.201122409f;          // sqrt(log2(e))
    float lnT2[KS];
#pragma unroll
    for (int i = 0; i < KS; ++i) {
        float r = (float)(i - RAD);
        lnT2[i] = -0.5f * r * r * isig2 * L2E;
    }

    // ---- issue guide loads (132 quad-tasks), then group-0 input loads ----
    float4 gX = make_float4(0.f, 0.f, 0.f, 0.f), gY = gX, gZ = gX;
    int grow = 0, gq = 0;
    if (tid < HR * NQ) {
        grow = tid / NQ; gq = tid - grow * NQ;
        int gy  = y0 - RAD + grow;
        int gxb = x0 - 4 + 4 * gq;                // 4-aligned quad
        if (gy >= 0 && gy < H && gxb >= 0 && gxb < W) {
            const float* p = gb + gy * W + gxb;
            gX = *(const float4*)p;
            gY = *(const float4*)(p + HWp);
            gZ = *(const float4*)(p + 2 * HWp);
        }
    }
    float4 iA[3], iB[3];
    ISSUE_IN(0);                                  // g0 loads fly under guide+weights

    // ---- guide pack + LDS write (halo cols 4q-1 .. 4q+2) ----
    if (tid < HR * NQ) {
        int base = grow * ROWST;
        const float xs[4] = {gX.x, gX.y, gX.z, gX.w};
        const float ys[4] = {gY.x, gY.y, gY.z, gY.w};
        const float zs[4] = {gZ.x, gZ.y, gZ.z, gZ.w};
        const int   st[4] = {base + PAIRS + 2 * gq - 1, base + 2 * gq,
                             base + PAIRS + 2 * gq,     base + 2 * gq + 1};
#pragma unroll
        for (int j = 0; j < 4; ++j) {
            if ((gq == 0 && j == 0) || (gq == NQ - 1 && j == 3)) continue;
            float ax = xs[j] * SQL, ay = ys[j] * SQL, az = zs[j] * SQL;
            float qv = -0.5f * (ax * ax + ay * ay + az * az);
            gt2[st[j]] = make_uint2(pk(ax, ay), pk(az, qv));
        }
    }
    __syncthreads();                              // gt2 ready

    // ---- per-column site offsets (hoisted) ----
    int colAdd[KS];
#pragma unroll
    for (int k = 0; k < KS; ++k) {
        int col = tx + k;
        colAdd[k] = (col & 1) * PAIRS + (col >> 1);
    }

    // ---- weights (g0 loads in flight underneath) ----
    const int ccol = tx + RAD;
    uint2 cr = gt2[(ty + RAD) * ROWST + (ccol & 1) * PAIRS + (ccol >> 1)];
    const f16x2 cxy = bch(cr.x);
    f16x2 czq = bch(cr.y);
    const float qc = (float)czq.y;
    f16x2 cz1;
    cz1.x = czq.x; cz1.y = (_Float16)1.0f;

    unsigned wkp[KS * KS];
    float nsum = 0.f;
#pragma unroll
    for (int i = 0; i < KS; ++i) {
        const int rb = (ty + i) * ROWST;
        const float Qi = lnT2[i] + qc;
#pragma unroll
        for (int k = 0; k < KS; ++k) {
            uint2 g = gt2[rb + colAdd[k]];
            float e = fdot2(bch(g.x), cxy, fdot2(bch(g.y), cz1, Qi + lnT2[k]));
            float w = exp2f(e);
            nsum += w;
            wkp[i * KS + k] = pk(w, w);
        }
    }
    const float inv = 1.f / nsum;   // >= center weight ~= 1, never 0
    const int Xo = x0 + tx, Yo = y0 + ty;

    // ---- pipeline: barrier -> [issue g+1 || apply g -> write g+1] ----
    WRITE_IN(0);
    __syncthreads();              // dtu[0] ready
    ISSUE_IN(1);                  // loads fly under apply(0)
    APPLY(0);
    WRITE_IN(1);
    __syncthreads();              // dtu[1] ready
    ISSUE_IN(2);
    APPLY(1);
    WRITE_IN(2);
    __syncthreads();              // dtu[2] ready
    ISSUE_IN(3);
    APPLY(2);
    WRITE_IN(3);
    __syncthreads();              // dtu[3] ready
    APPLY(3);
}

extern "C" void kernel_launch(void* const* d_in, const int* in_sizes, int n_in,
                              void* d_out, int out_size, void* d_ws, size_t ws_size,
                              hipStream_t stream) {
    const float* in    = (const float*)d_in[0];
    const float* guide = (const float*)d_in[1];
    const float* sigma = (const float*)d_in[2];
    float* out = (float*)d_out;
    dim3 grid(W / TW, H / TH, 2);   // 16 x 16 x 2 = 512 blocks, 2 per CU
    bilateral_kernel<<<grid, dim3(NTHR), 0, stream>>>(in, guide, sigma, out);
}

// Round 22
// 21.011 us; speedup vs baseline: 2.0166x; 1.1850x over previous
//
#include <hip/hip_runtime.h>

#define KS    7
#define RAD   3
#define TW    32            // tile width (output px)
#define TH    8             // tile height (2 independent blocks/CU)
#define HR    14            // halo rows = TH + 2*RAD
#define PAIRS 21            // col-pairs per parity row (19 needed, +2 pad)
#define NSITE (HR*2*PAIRS)  // 588 sites
#define H     256
#define W     256
#define HWp   (H*W)
#define NTASK (HR*10*4)     // 560 input staging tasks per group

typedef __fp16    h2raw __attribute__((ext_vector_type(2)));
typedef _Float16  f16x2 __attribute__((ext_vector_type(2)));

__device__ __forceinline__ unsigned pk(float a, float b) {
    h2raw h = __builtin_amdgcn_cvt_pkrtz(a, b);
    return __builtin_bit_cast(unsigned, h);
}
__device__ __forceinline__ f16x2 bch(unsigned u) {
    return __builtin_bit_cast(f16x2, u);
}

#if __has_builtin(__builtin_amdgcn_fdot2)
__device__ __forceinline__ float fdot2(f16x2 a, f16x2 b, float c) {
    return __builtin_amdgcn_fdot2(a, b, c, false);
}
#else
__device__ __forceinline__ float fdot2(f16x2 a, f16x2 b, float c) {
    return c + (float)a.x * (float)b.x + (float)a.y * (float)b.y;
}
#endif

// raw v_exp_f32 (no libm range fixups; exact for our e in [-90, 0])
#if __has_builtin(__builtin_amdgcn_exp2f)
__device__ __forceinline__ float fexp2(float x) { return __builtin_amdgcn_exp2f(x); }
#else
__device__ __forceinline__ float fexp2(float x) { return exp2f(x); }
#endif

// guaranteed packed fma: d = a*b + d (one v_pk_fma_f16; reg-only, dep-ordered)
__device__ __forceinline__ void pkfma(f16x2& d, f16x2 a, f16x2 b) {
    asm("v_pk_fma_f16 %0, %1, %2, %0" : "+v"(d) : "v"(a), "v"(b));
}

// ---- issue group g's global loads into registers (no LDS touch) ----
#define ISSUE_IN(g) do {                                                    \
    _Pragma("unroll")                                                       \
    for (int j = 0; j < 3; ++j) {                                           \
        int t = tid + j * 256;                                              \
        iA[j] = make_float4(0.f, 0.f, 0.f, 0.f); iB[j] = iA[j];             \
        if (t < NTASK) {                                                    \
            int row = t / 40;                                               \
            int rem = t - row * 40;                                         \
            int q   = rem >> 2;                                             \
            int cp  = rem & 3;                                              \
            int gy  = y0 - RAD + row;                                       \
            int gxb = x0 - 4 + 4 * q;                                       \
            if (gy >= 0 && gy < H && gxb >= 0 && gxb < W) {                 \
                const float* p = inb + (size_t)((g) * 8 + 2 * cp) * HWp     \
                                 + gy * W + gxb;                            \
                iA[j] = *(const float4*)p;                                  \
                iB[j] = *(const float4*)(p + HWp);                          \
            }                                                               \
        }                                                                   \
    }                                                                       \
} while (0)

// ---- pack staged registers and write them to dtu[g] ----
#define WRITE_IN(g) do {                                                    \
    _Pragma("unroll")                                                       \
    for (int j = 0; j < 3; ++j) {                                           \
        int t = tid + j * 256;                                              \
        if (t < NTASK) {                                                    \
            int row = t / 40;                                               \
            int rem = t - row * 40;                                         \
            int q   = rem >> 2;                                             \
            int cp  = rem & 3;                                              \
            int s0  = row * 2 * PAIRS + 2 * q;                              \
            unsigned* dst = &dtu[(g)][cp];                                  \
            if (q != 0) dst[(s0 + PAIRS - 1) * 4] = pk(iA[j].x, iB[j].x);   \
            dst[s0 * 4]           = pk(iA[j].y, iB[j].y);                   \
            dst[(s0 + PAIRS) * 4] = pk(iA[j].z, iB[j].z);                   \
            if (q != 9) dst[(s0 + 1) * 4] = pk(iA[j].w, iB[j].w);           \
        }                                                                   \
    }                                                                       \
} while (0)

// ---- apply group g: packed fma core, fp16 chains flushed at i==3 and end ----
#define APPLY(g) do {                                                       \
    const uint4* dg = (const uint4*)&dtu[(g)][0];                           \
    float acc[8];                                                           \
    _Pragma("unroll") for (int c = 0; c < 8; ++c) acc[c] = 0.f;             \
    f16x2 A0 = (f16x2)0, A1 = (f16x2)0, A2 = (f16x2)0, A3 = (f16x2)0;       \
    _Pragma("unroll")                                                       \
    for (int i = 0; i < KS; ++i) {                                          \
        const int rb = (ty + i) * 2 * PAIRS;                                \
        uint4 rq[KS];                                                       \
        _Pragma("unroll")                                                   \
        for (int k = 0; k < KS; ++k) rq[k] = dg[rb + colAdd[k]];            \
        _Pragma("unroll")                                                   \
        for (int k = 0; k < KS; ++k) {                                      \
            f16x2 wh = bch(wkp[i * KS + k]);                                \
            pkfma(A0, wh, bch(rq[k].x));                                    \
            pkfma(A1, wh, bch(rq[k].y));                                    \
            pkfma(A2, wh, bch(rq[k].z));                                    \
            pkfma(A3, wh, bch(rq[k].w));                                    \
        }                                                                   \
        if (i == 3) {   /* bound fp16 chain at 28 taps (R14-proven) */      \
            acc[0] += (float)A0.x; acc[1] += (float)A0.y;                   \
            acc[2] += (float)A1.x; acc[3] += (float)A1.y;                   \
            acc[4] += (float)A2.x; acc[5] += (float)A2.y;                   \
            acc[6] += (float)A3.x; acc[7] += (float)A3.y;                   \
            A0 = (f16x2)0; A1 = (f16x2)0; A2 = (f16x2)0; A3 = (f16x2)0;     \
        }                                                                   \
    }                                                                       \
    acc[0] += (float)A0.x; acc[1] += (float)A0.y;                           \
    acc[2] += (float)A1.x; acc[3] += (float)A1.y;                           \
    acc[4] += (float)A2.x; acc[5] += (float)A2.y;                           \
    acc[6] += (float)A3.x; acc[7] += (float)A3.y;                           \
    float* ob = out + ((size_t)b * 32 + (g) * 8) * HWp                      \
                + (size_t)Yo * W + Xo;                                      \
    _Pragma("unroll")                                                       \
    for (int c = 0; c < 8; ++c) ob[(size_t)c * HWp] = acc[c] * inv;         \
} while (0)

__global__ __launch_bounds__(256)
void bilateral_kernel(const float* __restrict__ in,      // [B][32][H][W]
                      const float* __restrict__ guide,   // [B][3][H][W]
                      const float* __restrict__ sigma_p, // [1]
                      float* __restrict__ out)           // [B][32][H][W]
{
    // parity-split site: (row,col) -> (row*2 + (col&1))*PAIRS + (col>>1)
    __shared__ uint2 gt2[NSITE];                          // {pk(x~,y~), pk(z~,q~)}
    __shared__ __align__(16) unsigned dtu[4][NSITE * 4];  // 4 grp x 8ch fp16/site

    const int tid = threadIdx.x;
    const int tx  = tid & 31;            // output col 0..31
    const int ty  = tid >> 5;            // output row 0..7
    const int x0  = blockIdx.x * TW;
    const int y0  = blockIdx.y * TH;
    const int b   = blockIdx.z;

    const float* gb  = guide + (size_t)b * 3  * HWp;
    const float* inb = in    + (size_t)b * 32 * HWp;

    const float sigma = sigma_p[0];
    const float isig2 = 1.0f / (sigma * sigma);
    const float L2E   = 1.442695041f;          // log2(e)
    const float SQL   = 1.201122409f;          // sqrt(log2(e))
    float lnT2[KS];
#pragma unroll
    for (int i = 0; i < KS; ++i) {
        float r = (float)(i - RAD);
        lnT2[i] = -0.5f * r * r * isig2 * L2E;
    }

    // ---- issue guide loads (140 quad-tasks), then group-0 input loads ----
    float4 gX = make_float4(0.f, 0.f, 0.f, 0.f), gY = gX, gZ = gX;
    int grow = 0, gq = 0;
    if (tid < HR * 10) {
        grow = tid / 10; gq = tid - grow * 10;
        int gy  = y0 - RAD + grow;
        int gxb = x0 - 4 + 4 * gq;                // 4-aligned quad
        if (gy >= 0 && gy < H && gxb >= 0 && gxb < W) {
            const float* p = gb + gy * W + gxb;
            gX = *(const float4*)p;
            gY = *(const float4*)(p + HWp);
            gZ = *(const float4*)(p + 2 * HWp);
        }
    }
    float4 iA[3], iB[3];
    ISSUE_IN(0);                                  // g0 loads fly under guide+weights

    // ---- guide pack + LDS write ----
    if (tid < HR * 10) {
        int s0 = grow * 2 * PAIRS + 2 * gq;
        const float xs[4] = {gX.x, gX.y, gX.z, gX.w};
        const float ys[4] = {gY.x, gY.y, gY.z, gY.w};
        const float zs[4] = {gZ.x, gZ.y, gZ.z, gZ.w};
        const int   st[4] = {s0 + PAIRS - 1, s0, s0 + PAIRS, s0 + 1};
#pragma unroll
        for (int j = 0; j < 4; ++j) {
            if ((gq == 0 && j == 0) || (gq == 9 && j == 3)) continue;
            float ax = xs[j] * SQL, ay = ys[j] * SQL, az = zs[j] * SQL;
            float qv = -0.5f * (ax * ax + ay * ay + az * az);
            gt2[st[j]] = make_uint2(pk(ax, ay), pk(az, qv));
        }
    }
    __syncthreads();                              // gt2 ready

    // ---- per-column site offsets (hoisted) ----
    int colAdd[KS];
#pragma unroll
    for (int k = 0; k < KS; ++k) {
        int col = tx + k;
        colAdd[k] = (col & 1) * PAIRS + (col >> 1);
    }

    // ---- weights (g0 loads in flight underneath) ----
    const int ccol = tx + RAD;
    uint2 cr = gt2[(ty + RAD) * 2 * PAIRS + (ccol & 1) * PAIRS + (ccol >> 1)];
    const f16x2 cxy = bch(cr.x);
    f16x2 czq = bch(cr.y);
    const float qc = (float)czq.y;
    f16x2 cz1;
    cz1.x = czq.x; cz1.y = (_Float16)1.0f;

    unsigned wkp[KS * KS];
    float nsum = 0.f;
#pragma unroll
    for (int i = 0; i < KS; ++i) {
        const int rb = (ty + i) * 2 * PAIRS;
        const float Qi = lnT2[i] + qc;
#pragma unroll
        for (int k = 0; k < KS; ++k) {
            uint2 g = gt2[rb + colAdd[k]];
            float e = fdot2(bch(g.x), cxy, fdot2(bch(g.y), cz1, Qi + lnT2[k]));
            float w = fexp2(e);
            nsum += w;
            wkp[i * KS + k] = pk(w, w);
        }
    }
    const float inv = 1.f / nsum;   // >= center weight ~= 1, never 0
    const int Xo = x0 + tx, Yo = y0 + ty;

    // ---- pipeline: barrier -> [issue g+1 || apply g -> write g+1] ----
    WRITE_IN(0);
    __syncthreads();              // dtu[0] ready
    ISSUE_IN(1);                  // loads fly under apply(0)
    APPLY(0);
    WRITE_IN(1);
    __syncthreads();              // dtu[1] ready
    ISSUE_IN(2);
    APPLY(1);
    WRITE_IN(2);
    __syncthreads();              // dtu[2] ready
    ISSUE_IN(3);
    APPLY(2);
    WRITE_IN(3);
    __syncthreads();              // dtu[3] ready
    APPLY(3);
}

extern "C" void kernel_launch(void* const* d_in, const int* in_sizes, int n_in,
                              void* d_out, int out_size, void* d_ws, size_t ws_size,
                              hipStream_t stream) {
    const float* in    = (const float*)d_in[0];
    const float* guide = (const float*)d_in[1];
    const float* sigma = (const float*)d_in[2];
    float* out = (float*)d_out;
    dim3 grid(W / TW, H / TH, 2);   // 8 x 32 x 2 = 512 blocks, 2 per CU
    bilateral_kernel<<<grid, dim3(256), 0, stream>>>(in, guide, sigma, out);
}

// Round 23
// 20.867 us; speedup vs baseline: 2.0305x; 1.0069x over previous
//
#include <hip/hip_runtime.h>

#define KS    7
#define RAD   3
#define TW    32            // tile width (output px)
#define TH    8             // tile height (2 independent blocks/CU)
#define HR    14            // halo rows = TH + 2*RAD
#define PAIRS 21            // col-pairs per parity row (19 needed, +2 pad)
#define NSITE (HR*2*PAIRS)  // 588 sites
#define H     256
#define W     256
#define HWp   (H*W)
#define NTASK (HR*10*4)     // 560 input staging tasks per group

typedef __fp16    h2raw __attribute__((ext_vector_type(2)));
typedef _Float16  f16x2 __attribute__((ext_vector_type(2)));

__device__ __forceinline__ unsigned pk(float a, float b) {
    h2raw h = __builtin_amdgcn_cvt_pkrtz(a, b);
    return __builtin_bit_cast(unsigned, h);
}
__device__ __forceinline__ f16x2 bch(unsigned u) {
    return __builtin_bit_cast(f16x2, u);
}

#if __has_builtin(__builtin_amdgcn_fdot2)
__device__ __forceinline__ float fdot2(f16x2 a, f16x2 b, float c) {
    return __builtin_amdgcn_fdot2(a, b, c, false);
}
#else
__device__ __forceinline__ float fdot2(f16x2 a, f16x2 b, float c) {
    return c + (float)a.x * (float)b.x + (float)a.y * (float)b.y;
}
#endif

#if __has_builtin(__builtin_amdgcn_exp2f)
__device__ __forceinline__ float fexp2(float x) { return __builtin_amdgcn_exp2f(x); }
#else
__device__ __forceinline__ float fexp2(float x) { return exp2f(x); }
#endif

// guaranteed packed fma: d = a*b + d
__device__ __forceinline__ void pkfma(f16x2& d, f16x2 a, f16x2 b) {
    asm("v_pk_fma_f16 %0, %1, %2, %0" : "+v"(d) : "v"(a), "v"(b));
}

// barrier WITHOUT vmcnt drain: LDS writes visible (lgkmcnt 0), but global
// loads/stores stay in flight across the barrier (T4 counted-wait idea).
#define BAR() asm volatile("s_waitcnt lgkmcnt(0)\n\ts_barrier" ::: "memory")

// ---- issue group g's loads using hoisted per-j task state ----
#define ISSUE_IN(g) do {                                                    \
    _Pragma("unroll")                                                       \
    for (int j = 0; j < 3; ++j) {                                           \
        iA[j] = make_float4(0.f, 0.f, 0.f, 0.f); iB[j] = iA[j];             \
        if (tv[j]) {                                                        \
            const float* p = inb + (size_t)((g) * 8 + 2 * tcp[j]) * HWp     \
                             + toff[j];                                     \
            iA[j] = *(const float4*)p;                                      \
            iB[j] = *(const float4*)(p + HWp);                              \
        }                                                                   \
    }                                                                       \
} while (0)

// ---- pack staged registers and write them to dtu[g] ----
#define WRITE_IN(g) do {                                                    \
    _Pragma("unroll")                                                       \
    for (int j = 0; j < 3; ++j) {                                           \
        if (tok[j]) {                                                       \
            unsigned* dst = &dtu[(g)][tcp[j]];                              \
            int s0 = ts0[j];                                                \
            if (!tq0[j]) dst[(s0 + PAIRS - 1) * 4] = pk(iA[j].x, iB[j].x);  \
            dst[s0 * 4]           = pk(iA[j].y, iB[j].y);                   \
            dst[(s0 + PAIRS) * 4] = pk(iA[j].z, iB[j].z);                   \
            if (!tq9[j]) dst[(s0 + 1) * 4] = pk(iA[j].w, iB[j].w);          \
        }                                                                   \
    }                                                                       \
} while (0)

// ---- apply group g: packed fma core, fp16 chains flushed at i==3 and end ----
#define APPLY(g) do {                                                       \
    const uint4* dg = (const uint4*)&dtu[(g)][0];                           \
    float acc[8];                                                           \
    _Pragma("unroll") for (int c = 0; c < 8; ++c) acc[c] = 0.f;             \
    f16x2 A0 = (f16x2)0, A1 = (f16x2)0, A2 = (f16x2)0, A3 = (f16x2)0;       \
    _Pragma("unroll")                                                       \
    for (int i = 0; i < KS; ++i) {                                          \
        const int rb = (ty + i) * 2 * PAIRS;                                \
        uint4 rq[KS];                                                       \
        _Pragma("unroll")                                                   \
        for (int k = 0; k < KS; ++k) rq[k] = dg[rb + colAdd[k]];            \
        _Pragma("unroll")                                                   \
        for (int k = 0; k < KS; ++k) {                                      \
            f16x2 wh = bch(wkp[i * KS + k]);                                \
            pkfma(A0, wh, bch(rq[k].x));                                    \
            pkfma(A1, wh, bch(rq[k].y));                                    \
            pkfma(A2, wh, bch(rq[k].z));                                    \
            pkfma(A3, wh, bch(rq[k].w));                                    \
        }                                                                   \
        if (i == 3) {   /* bound fp16 chain at 28 taps (R14-proven) */      \
            acc[0] += (float)A0.x; acc[1] += (float)A0.y;                   \
            acc[2] += (float)A1.x; acc[3] += (float)A1.y;                   \
            acc[4] += (float)A2.x; acc[5] += (float)A2.y;                   \
            acc[6] += (float)A3.x; acc[7] += (float)A3.y;                   \
            A0 = (f16x2)0; A1 = (f16x2)0; A2 = (f16x2)0; A3 = (f16x2)0;     \
        }                                                                   \
    }                                                                       \
    acc[0] += (float)A0.x; acc[1] += (float)A0.y;                           \
    acc[2] += (float)A1.x; acc[3] += (float)A1.y;                           \
    acc[4] += (float)A2.x; acc[5] += (float)A2.y;                           \
    acc[6] += (float)A3.x; acc[7] += (float)A3.y;                           \
    float* ob = out + ((size_t)b * 32 + (g) * 8) * HWp                      \
                + (size_t)Yo * W + Xo;                                      \
    _Pragma("unroll")                                                       \
    for (int c = 0; c < 8; ++c) ob[(size_t)c * HWp] = acc[c] * inv;         \
} while (0)

__global__ __launch_bounds__(256)
void bilateral_kernel(const float* __restrict__ in,      // [B][32][H][W]
                      const float* __restrict__ guide,   // [B][3][H][W]
                      const float* __restrict__ sigma_p, // [1]
                      float* __restrict__ out)           // [B][32][H][W]
{
    // parity-split site: (row,col) -> (row*2 + (col&1))*PAIRS + (col>>1)
    __shared__ uint2 gt2[NSITE];                          // {pk(x~,y~), pk(z~,q~)}
    __shared__ __align__(16) unsigned dtu[4][NSITE * 4];  // 4 grp x 8ch fp16/site

    const int tid = threadIdx.x;
    const int tx  = tid & 31;            // output col 0..31
    const int ty  = tid >> 5;            // output row 0..7
    const int x0  = blockIdx.x * TW;
    const int y0  = blockIdx.y * TH;
    const int b   = blockIdx.z;

    const float* gb  = guide + (size_t)b * 3  * HWp;
    const float* inb = in    + (size_t)b * 32 * HWp;

    const float sigma = sigma_p[0];
    const float isig2 = 1.0f / (sigma * sigma);
    const float L2E   = 1.442695041f;          // log2(e)
    const float SQL   = 1.201122409f;          // sqrt(log2(e))
    float lnT2[KS];
#pragma unroll
    for (int i = 0; i < KS; ++i) {
        float r = (float)(i - RAD);
        lnT2[i] = -0.5f * r * r * isig2 * L2E;
    }

    // ---- hoisted staging task state (group-invariant, computed ONCE) ----
    bool tok[3], tv[3], tq0[3], tq9[3];
    int  tcp[3], toff[3], ts0[3];
#pragma unroll
    for (int j = 0; j < 3; ++j) {
        int t = tid + j * 256;
        tok[j] = t < NTASK;
        int row = t / 40;
        int rem = t - row * 40;
        int q   = rem >> 2;
        tcp[j]  = rem & 3;
        int gy  = y0 - RAD + row;
        int gxb = x0 - 4 + 4 * q;
        tv[j]   = tok[j] && gy >= 0 && gy < H && gxb >= 0 && gxb < W;
        toff[j] = gy * W + gxb;
        ts0[j]  = row * 2 * PAIRS + 2 * q;
        tq0[j]  = (q == 0);
        tq9[j]  = (q == 9);
    }

    // ---- issue guide loads (140 quad-tasks), then group-0 input loads ----
    float4 gX = make_float4(0.f, 0.f, 0.f, 0.f), gY = gX, gZ = gX;
    int grow = 0, gq = 0;
    if (tid < HR * 10) {
        grow = tid / 10; gq = tid - grow * 10;
        int gy  = y0 - RAD + grow;
        int gxb = x0 - 4 + 4 * gq;                // 4-aligned quad
        if (gy >= 0 && gy < H && gxb >= 0 && gxb < W) {
            const float* p = gb + gy * W + gxb;
            gX = *(const float4*)p;
            gY = *(const float4*)(p + HWp);
            gZ = *(const float4*)(p + 2 * HWp);
        }
    }
    float4 iA[3], iB[3];
    ISSUE_IN(0);                                  // g0 loads fly under guide+weights

    // ---- guide pack + LDS write ----
    if (tid < HR * 10) {
        int s0 = grow * 2 * PAIRS + 2 * gq;
        const float xs[4] = {gX.x, gX.y, gX.z, gX.w};
        const float ys[4] = {gY.x, gY.y, gY.z, gY.w};
        const float zs[4] = {gZ.x, gZ.y, gZ.z, gZ.w};
        const int   st[4] = {s0 + PAIRS - 1, s0, s0 + PAIRS, s0 + 1};
#pragma unroll
        for (int j = 0; j < 4; ++j) {
            if ((gq == 0 && j == 0) || (gq == 9 && j == 3)) continue;
            float ax = xs[j] * SQL, ay = ys[j] * SQL, az = zs[j] * SQL;
            float qv = -0.5f * (ax * ax + ay * ay + az * az);
            gt2[st[j]] = make_uint2(pk(ax, ay), pk(az, qv));
        }
    }
    BAR();                                        // gt2 ready (loads stay in flight)

    // ---- per-column site offsets (hoisted) ----
    int colAdd[KS];
#pragma unroll
    for (int k = 0; k < KS; ++k) {
        int col = tx + k;
        colAdd[k] = (col & 1) * PAIRS + (col >> 1);
    }

    // ---- weights (g0 loads in flight underneath) ----
    const int ccol = tx + RAD;
    uint2 cr = gt2[(ty + RAD) * 2 * PAIRS + (ccol & 1) * PAIRS + (ccol >> 1)];
    const f16x2 cxy = bch(cr.x);
    f16x2 czq = bch(cr.y);
    const float qc = (float)czq.y;
    f16x2 cz1;
    cz1.x = czq.x; cz1.y = (_Float16)1.0f;

    unsigned wkp[KS * KS];
    float nsum = 0.f;
#pragma unroll
    for (int i = 0; i < KS; ++i) {
        const int rb = (ty + i) * 2 * PAIRS;
        const float Qi = lnT2[i] + qc;
#pragma unroll
        for (int k = 0; k < KS; ++k) {
            uint2 g = gt2[rb + colAdd[k]];
            float e = fdot2(bch(g.x), cxy, fdot2(bch(g.y), cz1, Qi + lnT2[k]));
            float w = fexp2(e);
            nsum += w;
            wkp[i * KS + k] = pk(w, w);
        }
    }
    const float inv = 1.f / nsum;   // >= center weight ~= 1, never 0
    const int Xo = x0 + tx, Yo = y0 + ty;

    // ---- pipeline: write g, issue g+1 (flies across BAR), barrier, apply g ----
    WRITE_IN(0);
    ISSUE_IN(1);
    BAR();                        // dtu[0] ready; g1 loads + stores keep flying
    APPLY(0);
    WRITE_IN(1);
    ISSUE_IN(2);
    BAR();                        // dtu[1] ready
    APPLY(1);
    WRITE_IN(2);
    ISSUE_IN(3);
    BAR();                        // dtu[2] ready
    APPLY(2);
    WRITE_IN(3);
    BAR();                        // dtu[3] ready
    APPLY(3);
}

extern "C" void kernel_launch(void* const* d_in, const int* in_sizes, int n_in,
                              void* d_out, int out_size, void* d_ws, size_t ws_size,
                              hipStream_t stream) {
    const float* in    = (const float*)d_in[0];
    const float* guide = (const float*)d_in[1];
    const float* sigma = (const float*)d_in[2];
    float* out = (float*)d_out;
    dim3 grid(W / TW, H / TH, 2);   // 8 x 32 x 2 = 512 blocks, 2 per CU
    bilateral_kernel<<<grid, dim3(256), 0, stream>>>(in, guide, sigma, out);
}

// Round 24
// 19.581 us; speedup vs baseline: 2.1639x; 1.0657x over previous
//
#include <hip/hip_runtime.h>

#define KS    7
#define RAD   3
#define TW    32            // tile width (output px)
#define TH    8             // tile height (2 independent blocks/CU)
#define HR    14            // halo rows = TH + 2*RAD
#define PAIRS 21            // col-pairs per parity row (19 needed, +2 pad)
#define NSITE (HR*2*PAIRS)  // 588 sites
#define H     256
#define W     256
#define HWp   (H*W)
#define NTASK2 (HR*10*2)    // 280 staging tasks/group: (row, quad, ch-quad)

typedef __fp16    h2raw __attribute__((ext_vector_type(2)));
typedef _Float16  f16x2 __attribute__((ext_vector_type(2)));

__device__ __forceinline__ unsigned pk(float a, float b) {
    h2raw h = __builtin_amdgcn_cvt_pkrtz(a, b);
    return __builtin_bit_cast(unsigned, h);
}
__device__ __forceinline__ f16x2 bch(unsigned u) {
    return __builtin_bit_cast(f16x2, u);
}

#if __has_builtin(__builtin_amdgcn_fdot2)
__device__ __forceinline__ float fdot2(f16x2 a, f16x2 b, float c) {
    return __builtin_amdgcn_fdot2(a, b, c, false);
}
#else
__device__ __forceinline__ float fdot2(f16x2 a, f16x2 b, float c) {
    return c + (float)a.x * (float)b.x + (float)a.y * (float)b.y;
}
#endif

#if __has_builtin(__builtin_amdgcn_exp2f)
__device__ __forceinline__ float fexp2(float x) { return __builtin_amdgcn_exp2f(x); }
#else
__device__ __forceinline__ float fexp2(float x) { return exp2f(x); }
#endif

// guaranteed packed fma: d = a*b + d
__device__ __forceinline__ void pkfma(f16x2& d, f16x2 a, f16x2 b) {
    asm("v_pk_fma_f16 %0, %1, %2, %0" : "+v"(d) : "v"(a), "v"(b));
}

// barrier WITHOUT vmcnt drain (global loads/stores stay in flight)
#define BAR() asm volatile("s_waitcnt lgkmcnt(0)\n\ts_barrier" ::: "memory")

// ---- issue group g's loads: 4 channels (rows A..D) per task ----
#define ISSUE_IN(g) do {                                                    \
    _Pragma("unroll")                                                       \
    for (int j = 0; j < 2; ++j) {                                           \
        iA[j] = make_float4(0.f, 0.f, 0.f, 0.f);                            \
        iB[j] = iA[j]; iC[j] = iA[j]; iD[j] = iA[j];                        \
        if (tv[j]) {                                                        \
            const float* p = inb + (size_t)((g) * 8 + 4 * tcpp[j]) * HWp    \
                             + toff[j];                                     \
            iA[j] = *(const float4*)p;                                      \
            iB[j] = *(const float4*)(p + HWp);                              \
            iC[j] = *(const float4*)(p + 2 * HWp);                          \
            iD[j] = *(const float4*)(p + 3 * HWp);                          \
        }                                                                   \
    }                                                                       \
} while (0)

// ---- pack + b64-write staged registers to dtu[g] (words cpp*2, cpp*2+1) ----
#define WRITE_IN(g) do {                                                    \
    _Pragma("unroll")                                                       \
    for (int j = 0; j < 2; ++j) {                                           \
        if (tok[j]) {                                                       \
            unsigned* bp = &dtu[(g)][ts0[j] * 4 + tcpp[j] * 2];             \
            *(uint2*)bp = make_uint2(pk(iA[j].y, iB[j].y),                  \
                                     pk(iC[j].y, iD[j].y));                 \
            *(uint2*)(bp + PAIRS * 4) = make_uint2(pk(iA[j].z, iB[j].z),    \
                                                   pk(iC[j].z, iD[j].z));   \
            if (!tq0[j])                                                    \
                *(uint2*)(bp + (PAIRS - 1) * 4) =                           \
                    make_uint2(pk(iA[j].x, iB[j].x), pk(iC[j].x, iD[j].x)); \
            if (!tq9[j])                                                    \
                *(uint2*)(bp + 4) =                                         \
                    make_uint2(pk(iA[j].w, iB[j].w), pk(iC[j].w, iD[j].w)); \
        }                                                                   \
    }                                                                       \
} while (0)

// ---- apply group g: packed fma core, fp16 chains flushed at i==3 and end ----
#define APPLY(g) do {                                                       \
    const uint4* dg = (const uint4*)&dtu[(g)][0];                           \
    float acc[8];                                                           \
    _Pragma("unroll") for (int c = 0; c < 8; ++c) acc[c] = 0.f;             \
    f16x2 A0 = (f16x2)0, A1 = (f16x2)0, A2 = (f16x2)0, A3 = (f16x2)0;       \
    _Pragma("unroll")                                                       \
    for (int i = 0; i < KS; ++i) {                                          \
        const int rb = (ty + i) * 2 * PAIRS;                                \
        uint4 rq[KS];                                                       \
        _Pragma("unroll")                                                   \
        for (int k = 0; k < KS; ++k) rq[k] = dg[rb + colAdd[k]];            \
        _Pragma("unroll")                                                   \
        for (int k = 0; k < KS; ++k) {                                      \
            f16x2 wh = bch(wkp[i * KS + k]);                                \
            pkfma(A0, wh, bch(rq[k].x));                                    \
            pkfma(A1, wh, bch(rq[k].y));                                    \
            pkfma(A2, wh, bch(rq[k].z));                                    \
            pkfma(A3, wh, bch(rq[k].w));                                    \
        }                                                                   \
        if (i == 3) {   /* bound fp16 chain at 28 taps (R14-proven) */      \
            acc[0] += (float)A0.x; acc[1] += (float)A0.y;                   \
            acc[2] += (float)A1.x; acc[3] += (float)A1.y;                   \
            acc[4] += (float)A2.x; acc[5] += (float)A2.y;                   \
            acc[6] += (float)A3.x; acc[7] += (float)A3.y;                   \
            A0 = (f16x2)0; A1 = (f16x2)0; A2 = (f16x2)0; A3 = (f16x2)0;     \
        }                                                                   \
    }                                                                       \
    acc[0] += (float)A0.x; acc[1] += (float)A0.y;                           \
    acc[2] += (float)A1.x; acc[3] += (float)A1.y;                           \
    acc[4] += (float)A2.x; acc[5] += (float)A2.y;                           \
    acc[6] += (float)A3.x; acc[7] += (float)A3.y;                           \
    float* ob = out + ((size_t)b * 32 + (g) * 8) * HWp                      \
                + (size_t)Yo * W + Xo;                                      \
    _Pragma("unroll")                                                       \
    for (int c = 0; c < 8; ++c) ob[(size_t)c * HWp] = acc[c] * inv;         \
} while (0)

__global__ __launch_bounds__(256)
void bilateral_kernel(const float* __restrict__ in,      // [B][32][H][W]
                      const float* __restrict__ guide,   // [B][3][H][W]
                      const float* __restrict__ sigma_p, // [1]
                      float* __restrict__ out)           // [B][32][H][W]
{
    // parity-split site: (row,col) -> (row*2 + (col&1))*PAIRS + (col>>1)
    __shared__ uint2 gt2[NSITE];                          // {pk(x~,y~), pk(z~,q~)}
    __shared__ __align__(16) unsigned dtu[4][NSITE * 4];  // 4 grp x 8ch fp16/site

    const int tid = threadIdx.x;
    const int tx  = tid & 31;            // output col 0..31
    const int ty  = tid >> 5;            // output row 0..7
    const int x0  = blockIdx.x * TW;
    const int y0  = blockIdx.y * TH;
    const int b   = blockIdx.z;

    const float* gb  = guide + (size_t)b * 3  * HWp;
    const float* inb = in    + (size_t)b * 32 * HWp;

    const float sigma = sigma_p[0];
    const float isig2 = 1.0f / (sigma * sigma);
    const float L2E   = 1.442695041f;          // log2(e)
    const float SQL   = 1.201122409f;          // sqrt(log2(e))
    float lnT2[KS];
#pragma unroll
    for (int i = 0; i < KS; ++i) {
        float r = (float)(i - RAD);
        lnT2[i] = -0.5f * r * r * isig2 * L2E;
    }

    // ---- hoisted staging task state: (row, quad q, ch-quad cpp) ----
    bool tok[2], tv[2], tq0[2], tq9[2];
    int  tcpp[2], toff[2], ts0[2];
#pragma unroll
    for (int j = 0; j < 2; ++j) {
        int t = tid + j * 256;
        tok[j] = t < NTASK2;
        int row = t / 20;
        int rem = t - row * 20;
        int q   = rem >> 1;
        tcpp[j] = rem & 1;
        int gy  = y0 - RAD + row;
        int gxb = x0 - 4 + 4 * q;
        tv[j]   = tok[j] && gy >= 0 && gy < H && gxb >= 0 && gxb < W;
        toff[j] = gy * W + gxb;
        ts0[j]  = row * 2 * PAIRS + 2 * q;
        tq0[j]  = (q == 0);
        tq9[j]  = (q == 9);
    }

    // ---- issue guide loads (140 quad-tasks), then group-0 input loads ----
    float4 gX = make_float4(0.f, 0.f, 0.f, 0.f), gY = gX, gZ = gX;
    int grow = 0, gq = 0;
    if (tid < HR * 10) {
        grow = tid / 10; gq = tid - grow * 10;
        int gy  = y0 - RAD + grow;
        int gxb = x0 - 4 + 4 * gq;                // 4-aligned quad
        if (gy >= 0 && gy < H && gxb >= 0 && gxb < W) {
            const float* p = gb + gy * W + gxb;
            gX = *(const float4*)p;
            gY = *(const float4*)(p + HWp);
            gZ = *(const float4*)(p + 2 * HWp);
        }
    }
    float4 iA[2], iB[2], iC[2], iD[2];
    ISSUE_IN(0);                                  // g0 loads fly under guide+weights

    // ---- guide pack + LDS write ----
    if (tid < HR * 10) {
        int s0 = grow * 2 * PAIRS + 2 * gq;
        const float xs[4] = {gX.x, gX.y, gX.z, gX.w};
        const float ys[4] = {gY.x, gY.y, gY.z, gY.w};
        const float zs[4] = {gZ.x, gZ.y, gZ.z, gZ.w};
        const int   st[4] = {s0 + PAIRS - 1, s0, s0 + PAIRS, s0 + 1};
#pragma unroll
        for (int j = 0; j < 4; ++j) {
            if ((gq == 0 && j == 0) || (gq == 9 && j == 3)) continue;
            float ax = xs[j] * SQL, ay = ys[j] * SQL, az = zs[j] * SQL;
            float qv = -0.5f * (ax * ax + ay * ay + az * az);
            gt2[st[j]] = make_uint2(pk(ax, ay), pk(az, qv));
        }
    }
    BAR();                                        // gt2 ready (loads stay in flight)

    // ---- per-column site offsets (hoisted) ----
    int colAdd[KS];
#pragma unroll
    for (int k = 0; k < KS; ++k) {
        int col = tx + k;
        colAdd[k] = (col & 1) * PAIRS + (col >> 1);
    }

    // ---- weights (g0 loads in flight underneath) ----
    const int ccol = tx + RAD;
    uint2 cr = gt2[(ty + RAD) * 2 * PAIRS + (ccol & 1) * PAIRS + (ccol >> 1)];
    const f16x2 cxy = bch(cr.x);
    f16x2 czq = bch(cr.y);
    const float qc = (float)czq.y;
    f16x2 cz1;
    cz1.x = czq.x; cz1.y = (_Float16)1.0f;

    unsigned wkp[KS * KS];
    float nsum = 0.f;
#pragma unroll
    for (int i = 0; i < KS; ++i) {
        const int rb = (ty + i) * 2 * PAIRS;
        const float Qi = lnT2[i] + qc;
#pragma unroll
        for (int k = 0; k < KS; ++k) {
            uint2 g = gt2[rb + colAdd[k]];
            float e = fdot2(bch(g.x), cxy, fdot2(bch(g.y), cz1, Qi + lnT2[k]));
            float w = fexp2(e);
            nsum += w;
            wkp[i * KS + k] = pk(w, w);
        }
    }
    const float inv = 1.f / nsum;   // >= center weight ~= 1, never 0
    const int Xo = x0 + tx, Yo = y0 + ty;

    // ---- pipeline: write g, issue g+1 (flies across BAR), barrier, apply g ----
    WRITE_IN(0);
    ISSUE_IN(1);
    BAR();                        // dtu[0] ready; g1 loads + stores keep flying
    APPLY(0);
    WRITE_IN(1);
    ISSUE_IN(2);
    BAR();                        // dtu[1] ready
    APPLY(1);
    WRITE_IN(2);
    ISSUE_IN(3);
    BAR();                        // dtu[2] ready
    APPLY(2);
    WRITE_IN(3);
    BAR();                        // dtu[3] ready
    APPLY(3);
}

extern "C" void kernel_launch(void* const* d_in, const int* in_sizes, int n_in,
                              void* d_out, int out_size, void* d_ws, size_t ws_size,
                              hipStream_t stream) {
    const float* in    = (const float*)d_in[0];
    const float* guide = (const float*)d_in[1];
    const float* sigma = (const float*)d_in[2];
    float* out = (float*)d_out;
    dim3 grid(W / TW, H / TH, 2);   // 8 x 32 x 2 = 512 blocks, 2 per CU
    bilateral_kernel<<<grid, dim3(256), 0, stream>>>(in, guide, sigma, out);
}